// Round 11
// baseline (870.941 us; speedup 1.0000x reference)
//
#include <hip/hip_runtime.h>
#include <math.h>

// VGG_RP round 11: KPH=2 for convrow (L1/L2/L3) — stage 2 kc-chunks per
// phase, 288 MFMA/wave between barriers (was 144), halving barrier count
// (precedent: r5 convpool KPH 1->2 = -9%). LDS 69.6KB (L1/L2) / 36.9KB (L3),
// still 2 blocks/CU. Math/swizzle/sync identical to r10 (passed, 866us).
// L0, L4 (split-tap convpool), RPN, heads, fc, nms unchanged.
//
// d_out (float32), out_size = 24640:
//   [0,640) logits | [640,3040) rp_cls | [3040,12640) rp_reg
//   [12640,22240) bboxes | [22240,24640) keep

#define OFF_LOGITS 0
#define OFF_CLS    640
#define OFF_REG    3040
#define OFF_BOXES  12640
#define OFF_KEEP   22240

constexpr int BATCH = 32;

typedef _Float16 h8 __attribute__((ext_vector_type(8)));
typedef _Float16 h4 __attribute__((ext_vector_type(4)));
typedef float    f4 __attribute__((ext_vector_type(4)));

#define MFMA16(a, b, c) __builtin_amdgcn_mfma_f32_16x16x32_f16(a, b, c, 0, 0, 0)

#if defined(__has_builtin)
#  if __has_builtin(__builtin_amdgcn_global_load_lds)
#    define HAS_GLL 1
#  endif
#endif

// async global->LDS, 16B per lane. lbase must be wave-uniform (HW adds lane*16).
__device__ __forceinline__ void stage16(const _Float16* g, _Float16* lbase, int lane) {
#ifdef HAS_GLL
  __builtin_amdgcn_global_load_lds((const __attribute__((address_space(1))) void*)g,
                                   (__attribute__((address_space(3))) void*)lbase,
                                   16, 0, 0);
#else
  *reinterpret_cast<h8*>(lbase + lane * 8) = *reinterpret_cast<const h8*>(g);
#endif
}

// ---------------- workspace layout (bytes) ----------------
constexpr size_t A_OFF = 0;              // I0 -> I2 -> {I4, feat, rp512, partials}
constexpr size_t B_OFF = 106463232;      // I1 -> I3
constexpr size_t W_OFF = 161579008;      // converted weights
constexpr size_t P_OFF = A_OFF + 8388608;  // partials (overlay dead I2 region)

constexpr int I0_E = 26615808;   // 32*114*114*64
constexpr int I1_E = 13778944;   // 32*58*58*128
constexpr int I2_E = 7372800;    // 32*30*30*256
constexpr int I3_E = 4194304;    // 32*16*16*512
constexpr int I4_E = 802816;     // 32*7*7*512

// ---------------- weight convert: OIHW fp32 -> [tap*kch][co][32] hi/lo ------
__global__ __launch_bounds__(256)
void wcvt(const float* __restrict__ src, _Float16* __restrict__ dHi,
          _Float16* __restrict__ dLo, int COUT, int CIN) {
  const int total = COUT * CIN * 9;
  for (int idx = blockIdx.x * 256 + threadIdx.x; idx < total; idx += gridDim.x * 256) {
    const int co = idx / (CIN * 9);
    const int r = idx % (CIN * 9);
    const int ci = r / 9, tap = r % 9;
    const float v = src[idx];
    const _Float16 h = (_Float16)v;
    const int o = ((tap * (CIN >> 5) + (ci >> 5)) * COUT + co) * 32 + (ci & 31);
    dHi[o] = h;
    dLo[o] = (_Float16)(v - (float)h);
  }
}

// ---------------- zero the 1-px pad ring of a CL fp16 buffer ----------------
__global__ __launch_bounds__(256)
void zero_ring(_Float16* __restrict__ hi, _Float16* __restrict__ lo, int P, int C) {
  const int c8n = C / 8, cells = 4 * P - 4;
  const int tot = 32 * cells * c8n;
  for (int idx = blockIdx.x * 256 + threadIdx.x; idx < tot; idx += gridDim.x * 256) {
    const int c8 = idx % c8n;
    const int cell = (idx / c8n) % cells;
    const int n = idx / (c8n * cells);
    int y, xx;
    if (cell < 2 * P) { y = (cell < P) ? 0 : (P - 1); xx = cell % P; }
    else { const int q = cell - 2 * P; y = 1 + (q >> 1); xx = (q & 1) ? (P - 1) : 0; }
    const long o = ((long)(n * P + y) * P + xx) * C + c8 * 8;
    h8 z = {};
    *reinterpret_cast<h8*>(hi + o) = z;
    *reinterpret_cast<h8*>(lo + o) = z;
  }
}

// ---------------- L0: 3->64 direct fp32 conv+pool, LDS-staged output --------
constexpr int L0_SW   = 0;              // 1728 floats
constexpr int L0_SB   = 6912;           // 64 floats
constexpr int L0_SIN  = 7168;           // 3*34*34 floats (dead after win load)
constexpr int L0_HI   = 7168;           // 256 px * 144B (overlays sIn)
constexpr int L0_LO   = 7168 + 36864;   // 256 px * 144B
constexpr int L0_LDS  = 7168 + 73728;   // 80,896 B total

__global__ __launch_bounds__(256)
void conv_l0(const float* __restrict__ x, const float* __restrict__ w0,
             const float* __restrict__ b0, _Float16* __restrict__ outHi,
             _Float16* __restrict__ outLo) {
  const int bid = blockIdx.x;
  const int tx0 = (bid % 7) * 16, ty0 = ((bid / 7) % 7) * 16, n = bid / 49;
  __align__(16) __shared__ char lds[L0_LDS];
  float* sW = (float*)(lds + L0_SW);
  float* sB = (float*)(lds + L0_SB);
  float* sIn = (float*)(lds + L0_SIN);
  const int tid = threadIdx.x;
  for (int idx = tid; idx < 3 * 34 * 34; idx += 256) {
    const int ci = idx / 1156, rem = idx % 1156, r = rem / 34, cc = rem % 34;
    const int y = 2 * ty0 - 1 + r, xx = 2 * tx0 - 1 + cc;
    float v = 0.f;
    if ((unsigned)y < 224u && (unsigned)xx < 224u)
      v = x[((n * 3 + ci) * 224 + y) * 224 + xx];
    sIn[idx] = v;
  }
  for (int idx = tid; idx < 1728; idx += 256) sW[idx] = w0[idx];
  if (tid < 64) sB[tid] = b0[tid];
  __syncthreads();

  const int tpy = tid / 16, tpx = tid % 16;
  float win[3][4][4];
  #pragma unroll
  for (int ci = 0; ci < 3; ++ci)
    #pragma unroll
    for (int dr = 0; dr < 4; ++dr)
      #pragma unroll
      for (int dc = 0; dc < 4; ++dc)
        win[ci][dr][dc] = sIn[ci * 1156 + (2 * tpy + dr) * 34 + (2 * tpx + dc)];
  __syncthreads();  // all reads of sIn done before sOut overlays it

  for (int co4 = 0; co4 < 16; ++co4) {
    h4 hh, ll;
    #pragma unroll
    for (int j = 0; j < 4; ++j) {
      const int co = co4 * 4 + j;
      float a00 = 0.f, a01 = 0.f, a10 = 0.f, a11 = 0.f;
      #pragma unroll
      for (int ci = 0; ci < 3; ++ci)
        #pragma unroll
        for (int ky = 0; ky < 3; ++ky)
          #pragma unroll
          for (int kx = 0; kx < 3; ++kx) {
            const float wv = sW[co * 27 + ci * 9 + ky * 3 + kx];
            a00 = fmaf(win[ci][ky][kx], wv, a00);
            a01 = fmaf(win[ci][ky][kx + 1], wv, a01);
            a10 = fmaf(win[ci][ky + 1][kx], wv, a10);
            a11 = fmaf(win[ci][ky + 1][kx + 1], wv, a11);
          }
      const float p = fmaxf(fmaxf(fmaxf(a00, a01), fmaxf(a10, a11)) + sB[co], 0.f);
      const _Float16 h = (_Float16)p;
      hh[j] = h;
      ll[j] = (_Float16)(p - (float)h);
    }
    *reinterpret_cast<h4*>(lds + L0_HI + tid * 144 + co4 * 8) = hh;
    *reinterpret_cast<h4*>(lds + L0_LO + tid * 144 + co4 * 8) = ll;
  }
  __syncthreads();

  const int tr_half = tid >> 7;
  const int pixrow = (tid & 127) >> 3;
  const int ch8 = (tid & 7) * 8;
  #pragma unroll
  for (int i = 0; i < 8; ++i) {
    const int tr = 2 * i + tr_half;
    const int pix = tr * 16 + pixrow;
    const long ga = ((long)(n * 114 + ty0 + tr + 1) * 114 + tx0 + pixrow + 1) * 64 + ch8;
    *reinterpret_cast<h8*>(outHi + ga) =
        *reinterpret_cast<const h8*>(lds + L0_HI + pix * 144 + ch8 * 2);
    *reinterpret_cast<h8*>(outLo + ga) =
        *reinterpret_cast<const h8*>(lds + L0_LO + pix * 144 + ch8 * 2);
  }
}

// ---------------- convrow: tap-reuse row-tile conv+pool (L1/L2/L3) ----------
// Block = (n, py, xh) x co-split blockIdx.y. Stages STG rows per kc-chunk,
// KPH chunks per phase (288 MFMA/wave per barrier at KPH=2); kx taps read
// the same staged tile at +2*kx. 4 waves = NCOW co x (4/NCOW) sp.
template<int CIN, int COUT, int H, int XH, int NCOW, int STG, int SARR, int KPH>
__global__ __launch_bounds__(256, 2)
void convrow(const _Float16* __restrict__ inHi, const _Float16* __restrict__ inLo,
             const _Float16* __restrict__ wHi, const _Float16* __restrict__ wLo,
             const float* __restrict__ bias, _Float16* __restrict__ outHi,
             _Float16* __restrict__ outLo) {
  constexpr int W = H, Hp = H / 2, Wp = W / 2, PW = W + 2, POW = Wp + 2;
  constexpr int KCH = CIN / 32;
  constexpr int NCH = 3 * KCH;         // (ky, kc) chunks
  constexpr int NGRP = NCH / KPH;      // barrier groups
  static_assert(NCH % KPH == 0, "even groups");
  constexpr int NSPW = 4 / NCOW;       // sp waves
  constexpr int NFULL = STG / 64;      // full staging rounds
  constexpr int TAIL = STG % 64;       // tail rows (staged by tid < TAIL*4)
  constexpr int TSZ = SARR * 32;       // elements per (hl, j) tile
  static_assert(NSPW * 64 + 3 < STG + 1, "staged rows cover shifted reads");
  __align__(16) __shared__ _Float16 sB[2][2][KPH][TSZ];

  const int tid = threadIdx.x;
  const int lane = tid & 63, wv = tid >> 6;
  const int c = lane & 15, kq = lane >> 4;
  const int cow = blockIdx.y * (NCOW * 64) + (wv % NCOW) * 64;
  const int spl = (wv / NCOW) * 64;
  const int xh = blockIdx.x % XH;
  const int pyn = blockIdx.x / XH;
  const int py = pyn % Hp, n = pyn / Hp;
  const int x0 = xh * 64;

  // staging sources (ky=0,kc=0 base; per-chunk add ky*PW*CIN + kc*32)
  int gstage[NFULL + 1];
  #pragma unroll
  for (int i = 0; i < NFULL + 1; ++i) {
    const int sl = i * 64 + tid / 4;
    const int ry = sl & 1;
    int xx = x0 + (sl >> 1);
    if (xx > PW - 1) xx = PW - 1;      // clamp into right zero-pad col
    gstage[i] = ((n * (H + 2) + 2 * py + ry) * PW + xx) * CIN +
                (((tid & 3) ^ ((sl >> 1) & 3)) * 8);
  }
  // ds_read offsets per (kx, nt), swizzled
  int dsoff[3][4];
  #pragma unroll
  for (int kx = 0; kx < 3; ++kx)
    #pragma unroll
    for (int nt = 0; nt < 4; ++nt) {
      const int r = spl + nt * 16 + c + 2 * kx;
      dsoff[kx][nt] = r * 32 + ((kq ^ ((r >> 1) & 3)) * 8);
    }

  // prologue: stage group 0 (KPH chunks) into buf 0
  #pragma unroll
  for (int j = 0; j < KPH; ++j) {
    const int tb = (j / KCH) * PW * CIN + (j % KCH) * 32;
    #pragma unroll
    for (int i = 0; i < NFULL; ++i) {
      stage16(inHi + gstage[i] + tb, &sB[0][0][j][i * 2048 + wv * 512], lane);
      stage16(inLo + gstage[i] + tb, &sB[0][1][j][i * 2048 + wv * 512], lane);
    }
    if (TAIL && tid < TAIL * 4) {
      stage16(inHi + gstage[NFULL] + tb, &sB[0][0][j][NFULL * 2048], lane);
      stage16(inLo + gstage[NFULL] + tb, &sB[0][1][j][NFULL * 2048], lane);
    }
  }
  __syncthreads();

  f4 acc[4][4] = {};
  int cur = 0;
  for (int g = 0; g < NGRP; ++g) {
    // stage next group into the other buffer (drains at the barrier)
    if (g + 1 < NGRP) {
      #pragma unroll
      for (int j2 = 0; j2 < KPH; ++j2) {
        const int ch2 = (g + 1) * KPH + j2;
        const int tb2 = (ch2 / KCH) * PW * CIN + (ch2 % KCH) * 32;
        #pragma unroll
        for (int i = 0; i < NFULL; ++i) {
          stage16(inHi + gstage[i] + tb2,
                  &sB[cur ^ 1][0][j2][i * 2048 + wv * 512], lane);
          stage16(inLo + gstage[i] + tb2,
                  &sB[cur ^ 1][1][j2][i * 2048 + wv * 512], lane);
        }
        if (TAIL && tid < TAIL * 4) {
          stage16(inHi + gstage[NFULL] + tb2, &sB[cur ^ 1][0][j2][NFULL * 2048], lane);
          stage16(inLo + gstage[NFULL] + tb2, &sB[cur ^ 1][1][j2][NFULL * 2048], lane);
        }
      }
    }
    // compute KPH chunks x 3 kx taps off the staged tiles
    #pragma unroll
    for (int j = 0; j < KPH; ++j) {
      const int ch = g * KPH + j;
      const int ky = ch / KCH, kc = ch % KCH;
      #pragma unroll
      for (int kx = 0; kx < 3; ++kx) {
        h8 aH[4], aL[4];
        const long abase = ((long)((ky * 3 + kx) * KCH + kc) * COUT + cow) * 32;
        #pragma unroll
        for (int mt = 0; mt < 4; ++mt) {
          const long ao = abase + (mt * 16 + c) * 32 + kq * 8;
          aH[mt] = *reinterpret_cast<const h8*>(wHi + ao);
          aL[mt] = *reinterpret_cast<const h8*>(wLo + ao);
        }
        h8 bH[4], bL[4];
        #pragma unroll
        for (int nt = 0; nt < 4; ++nt) {
          bH[nt] = *reinterpret_cast<const h8*>(&sB[cur][0][j][dsoff[kx][nt]]);
          bL[nt] = *reinterpret_cast<const h8*>(&sB[cur][1][j][dsoff[kx][nt]]);
        }
        __builtin_amdgcn_s_setprio(1);
        #pragma unroll
        for (int mt = 0; mt < 4; ++mt)
          #pragma unroll
          for (int nt = 0; nt < 4; ++nt)
            acc[mt][nt] = MFMA16(aH[mt], bH[nt], acc[mt][nt]);
        #pragma unroll
        for (int mt = 0; mt < 4; ++mt)
          #pragma unroll
          for (int nt = 0; nt < 4; ++nt)
            acc[mt][nt] = MFMA16(aH[mt], bL[nt], acc[mt][nt]);
        #pragma unroll
        for (int mt = 0; mt < 4; ++mt)
          #pragma unroll
          for (int nt = 0; nt < 4; ++nt)
            acc[mt][nt] = MFMA16(aL[mt], bH[nt], acc[mt][nt]);
        __builtin_amdgcn_s_setprio(0);
      }
    }
    __syncthreads();
    cur ^= 1;
  }

  // epilogue: 2x2 pool, bias+relu, guarded padded-CL write
  const int r4 = lane >> 4;
  #pragma unroll
  for (int mt = 0; mt < 4; ++mt) {
    const int co0 = cow + mt * 16 + r4 * 4;
    const f4 bi = *reinterpret_cast<const f4*>(bias + co0);
    #pragma unroll
    for (int nt = 0; nt < 4; ++nt) {
      f4 v = acc[mt][nt];
      #pragma unroll
      for (int r = 0; r < 4; ++r) {
        const float m1 = fmaxf(v[r], __shfl_xor(v[r], 1, 64));
        v[r] = fmaxf(m1, __shfl_xor(m1, 2, 64));
      }
      if ((lane & 3) == 0) {
        const int rr = spl + nt * 16 + c;
        const int pxg = xh * 32 + (rr >> 2);
        if (pxg < Wp) {
          h4 hh, ll;
          #pragma unroll
          for (int r = 0; r < 4; ++r) {
            const float p = fmaxf(v[r] + bi[r], 0.f);
            const _Float16 h = (_Float16)p;
            hh[r] = h;
            ll[r] = (_Float16)(p - (float)h);
          }
          const long oa = ((long)((n * (Hp + 2) + py + 1) * POW + pxg + 1)) * COUT + co0;
          *reinterpret_cast<h4*>(outHi + oa) = hh;
          *reinterpret_cast<h4*>(outLo + oa) = ll;
        }
      }
    }
  }
}

// ---------------- convpool: r8 3-buffer counted pipeline (L4 split-tap) -----
template<int CIN, int COUT, int H, int BCO, int BSP, int TG, int KPH, int MODE>
__global__ __launch_bounds__(256, 2)
void convpool(const _Float16* __restrict__ inHi, const _Float16* __restrict__ inLo,
              const _Float16* __restrict__ wHi, const _Float16* __restrict__ wLo,
              const float* __restrict__ bias, _Float16* __restrict__ outHi,
              _Float16* __restrict__ outLo, float* __restrict__ outF) {
  constexpr int W = H, Hp = H / 2, Wp = W / 2, PW = W + 2, POW = Wp + 2;
  constexpr int NCOW = BCO / 64, NSPW = BSP / 64;
  static_assert(NCOW * NSPW == 4, "4 waves");
  constexpr int KCH = CIN / 32;
  constexpr int NCH = TG * KCH;
  constexpr int NPH = NCH / KPH;
  static_assert(NCH % KPH == 0, "even phases");
  static_assert(KPH * 2 * (BSP / 64) == 4, "prologue vmcnt literal = 4");
  constexpr int NISS = BSP / 64;
  constexpr int SPTOT = 32 * H * W;
  constexpr int TSZ = BSP * 32;
  __align__(16) __shared__ _Float16 sB[3 * 2 * KPH * TSZ];
  #define TIDX(buf, hl, j) ((((buf) * 2 + (hl)) * KPH + (j)) * TSZ)

  const int tid = threadIdx.x;
  const int lane = tid & 63, wv = tid >> 6;
  const int c = lane & 15, kq = lane >> 4;
  const int cow = blockIdx.y * BCO + (wv % NCOW) * 64;
  const int spl = (wv / NCOW) * 64;
  const int sblk = blockIdx.x * BSP;
  const int tap0 = (TG == 9) ? 0 : blockIdx.z * TG;

  int gstage[NISS];
  #pragma unroll
  for (int i = 0; i < NISS; ++i) {
    const int sl = i * 64 + tid / 4;
    const int sg = sblk + sl;
    const int ry = sg & 1, tt = sg >> 1;
    const int x = tt % W, u = tt / W;
    const int py = u % Hp, n = u / Hp;
    gstage[i] = ((n * (H + 2) + 2 * py + ry) * PW + x) * CIN +
                (((tid & 3) ^ ((sl >> 1) & 3)) * 8);
  }
  int dsoff[4];
  #pragma unroll
  for (int nt = 0; nt < 4; ++nt) {
    const int row = spl + nt * 16 + c;
    dsoff[nt] = row * 32 + ((kq ^ ((row >> 1) & 3)) * 8);
  }

  #pragma unroll
  for (int pp = 0; pp < 2; ++pp) {
    #pragma unroll
    for (int j = 0; j < KPH; ++j) {
      const int ch = pp * KPH + j;
      const int tap = tap0 + ch / KCH, kc = ch % KCH;
      const int tb = ((tap / 3) * PW + (tap % 3)) * CIN + kc * 32;
      #pragma unroll
      for (int i = 0; i < NISS; ++i) {
        stage16(inHi + gstage[i] + tb, &sB[TIDX(pp, 0, j) + i * 2048 + wv * 512], lane);
        stage16(inLo + gstage[i] + tb, &sB[TIDX(pp, 1, j) + i * 2048 + wv * 512], lane);
      }
    }
  }
  __builtin_amdgcn_sched_barrier(0);
  asm volatile("s_waitcnt vmcnt(4)" ::: "memory");
  __builtin_amdgcn_sched_barrier(0);
  __builtin_amdgcn_s_barrier();
  __builtin_amdgcn_sched_barrier(0);

  f4 acc[4][4] = {};
  for (int ph = 0; ph < NPH; ++ph) {
    const int bp = ph % 3;
    h8 aH[KPH][4], aL[KPH][4];
    #pragma unroll
    for (int j = 0; j < KPH; ++j) {
      const int ch = ph * KPH + j;
      const int tap = tap0 + ch / KCH;
      const int kc = ch % KCH;
      const long abase = ((long)(tap * KCH + kc) * COUT + cow) * 32;
      #pragma unroll
      for (int mt = 0; mt < 4; ++mt) {
        const long ao = abase + (mt * 16 + c) * 32 + kq * 8;
        aH[j][mt] = *reinterpret_cast<const h8*>(wHi + ao);
        aL[j][mt] = *reinterpret_cast<const h8*>(wLo + ao);
      }
    }
    __builtin_amdgcn_sched_barrier(0);
    if (ph + 2 < NPH) {
      const int bs = (ph + 2) % 3;
      #pragma unroll
      for (int j2 = 0; j2 < KPH; ++j2) {
        const int ch2 = (ph + 2) * KPH + j2;
        const int tap2 = tap0 + ch2 / KCH;
        const int tb2 = ((tap2 / 3) * PW + (tap2 % 3)) * CIN + (ch2 % KCH) * 32;
        #pragma unroll
        for (int i = 0; i < NISS; ++i) {
          stage16(inHi + gstage[i] + tb2,
                  &sB[TIDX(bs, 0, j2) + i * 2048 + wv * 512], lane);
          stage16(inLo + gstage[i] + tb2,
                  &sB[TIDX(bs, 1, j2) + i * 2048 + wv * 512], lane);
        }
      }
    }
    __builtin_amdgcn_sched_barrier(0);
    #pragma unroll
    for (int j = 0; j < KPH; ++j) {
      h8 bH[4], bL[4];
      #pragma unroll
      for (int nt = 0; nt < 4; ++nt) {
        bH[nt] = *reinterpret_cast<const h8*>(&sB[TIDX(bp, 0, j) + dsoff[nt]]);
        bL[nt] = *reinterpret_cast<const h8*>(&sB[TIDX(bp, 1, j) + dsoff[nt]]);
      }
      __builtin_amdgcn_s_setprio(1);
      #pragma unroll
      for (int mt = 0; mt < 4; ++mt)
        #pragma unroll
        for (int nt = 0; nt < 4; ++nt)
          acc[mt][nt] = MFMA16(aH[j][mt], bH[nt], acc[mt][nt]);
      #pragma unroll
      for (int mt = 0; mt < 4; ++mt)
        #pragma unroll
        for (int nt = 0; nt < 4; ++nt)
          acc[mt][nt] = MFMA16(aH[j][mt], bL[nt], acc[mt][nt]);
      #pragma unroll
      for (int mt = 0; mt < 4; ++mt)
        #pragma unroll
        for (int nt = 0; nt < 4; ++nt)
          acc[mt][nt] = MFMA16(aL[j][mt], bH[nt], acc[mt][nt]);
      __builtin_amdgcn_s_setprio(0);
    }
    __builtin_amdgcn_sched_barrier(0);
    __builtin_amdgcn_s_barrier();
    __builtin_amdgcn_sched_barrier(0);
  }
  #undef TIDX

  const int r4 = lane >> 4;
  if (MODE == 1) {
    #pragma unroll
    for (int mt = 0; mt < 4; ++mt) {
      const int co0 = cow + mt * 16 + r4 * 4;
      #pragma unroll
      for (int nt = 0; nt < 4; ++nt) {
        const int s = sblk + spl + nt * 16 + c;
        *reinterpret_cast<f4*>(outF + ((long)blockIdx.z * SPTOT + s) * COUT + co0) =
            acc[mt][nt];
      }
    }
  } else {
    #pragma unroll
    for (int mt = 0; mt < 4; ++mt) {
      const int co0 = cow + mt * 16 + r4 * 4;
      const f4 bi = *reinterpret_cast<const f4*>(bias + co0);
      #pragma unroll
      for (int nt = 0; nt < 4; ++nt) {
        f4 v = acc[mt][nt];
        #pragma unroll
        for (int r = 0; r < 4; ++r) {
          const float m1 = fmaxf(v[r], __shfl_xor(v[r], 1, 64));
          v[r] = fmaxf(m1, __shfl_xor(m1, 2, 64));
        }
        if ((lane & 3) == 0) {
          const int s = sblk + spl + nt * 16 + c;
          const int ps = s >> 2;
          const int n = ps / (Hp * Wp), rem = ps % (Hp * Wp);
          const int py = rem / Wp, px = rem % Wp;
          h4 hh, ll;
          #pragma unroll
          for (int r = 0; r < 4; ++r) {
            const float p = fmaxf(v[r] + bi[r], 0.f);
            const _Float16 h = (_Float16)p;
            hh[r] = h;
            ll[r] = (_Float16)(p - (float)h);
          }
          const long oa = ((long)((n * (Hp + 2) + py + 1) * POW + px + 1)) * COUT + co0;
          *reinterpret_cast<h4*>(outHi + oa) = hh;
          *reinterpret_cast<h4*>(outLo + oa) = ll;
        }
      }
    }
  }
}

// ---------------- l4_finish: sum 3 partials, pool, bias, relu ---------------
__global__ __launch_bounds__(256)
void l4_finish(const float* __restrict__ part, const float* __restrict__ bias,
               _Float16* __restrict__ I4h, _Float16* __restrict__ I4l,
               float* __restrict__ feat) {
  const int t = blockIdx.x * 256 + threadIdx.x;
  if (t >= 1568 * 128) return;
  const int co0 = (t % 128) * 4, p = t / 128;
  f4 m;
  #pragma unroll
  for (int q = 0; q < 4; ++q) {
    const long s = 4L * p + q;
    f4 v = *reinterpret_cast<const f4*>(part + s * 512 + co0);
    v += *reinterpret_cast<const f4*>(part + (6272 + s) * 512 + co0);
    v += *reinterpret_cast<const f4*>(part + (12544 + s) * 512 + co0);
    if (q == 0) m = v;
    else {
      #pragma unroll
      for (int r = 0; r < 4; ++r) m[r] = fmaxf(m[r], v[r]);
    }
  }
  const f4 bi = *reinterpret_cast<const f4*>(bias + co0);
  h4 hh, ll;
  const int n = p / 49, pix = p % 49;
  #pragma unroll
  for (int r = 0; r < 4; ++r) {
    const float pv = fmaxf(m[r] + bi[r], 0.f);
    const _Float16 h = (_Float16)pv;
    hh[r] = h;
    ll[r] = (_Float16)(pv - (float)h);
    feat[((long)(n * 512 + co0 + r)) * 49 + pix] = pv;
  }
  *reinterpret_cast<h4*>(I4h + (long)p * 512 + co0) = hh;
  *reinterpret_cast<h4*>(I4l + (long)p * 512 + co0) = ll;
}

// ---------------- RPN partial: one tap per blockIdx.z, K=512 GEMM -----------
__global__ __launch_bounds__(256)
void rpn_partial(const _Float16* __restrict__ inHi, const _Float16* __restrict__ inLo,
                 const _Float16* __restrict__ wHi, const _Float16* __restrict__ wLo,
                 float* __restrict__ part) {
  const int lane = threadIdx.x & 63, wv = threadIdx.x >> 6;
  const int cow = blockIdx.y * 128 + wv * 32;
  const int sblk = blockIdx.x * 64;
  const int tap = blockIdx.z, ky = tap / 3, kx = tap % 3;
  const int c = lane & 15, kq = lane >> 4;

  int baseB[4];
  #pragma unroll
  for (int nt = 0; nt < 4; ++nt) {
    int s = sblk + nt * 16 + c;
    if (s > 799) s = 799;
    const int n = s / 25, pix = s % 25, py = pix / 5, px = pix % 5;
    baseB[nt] = ((n * 7 + py + ky) * 7 + px + kx) * 512;
  }

  f4 acc[2][4] = {};
  for (int kch = 0; kch < 16; ++kch) {
    h8 aH[2], aL[2], bH[4], bL[4];
    const long abase = ((long)(tap * 16 + kch) * 512 + cow) * 32;
    #pragma unroll
    for (int mt = 0; mt < 2; ++mt) {
      const long ao = abase + (mt * 16 + c) * 32 + kq * 8;
      aH[mt] = *reinterpret_cast<const h8*>(wHi + ao);
      aL[mt] = *reinterpret_cast<const h8*>(wLo + ao);
    }
    #pragma unroll
    for (int nt = 0; nt < 4; ++nt) {
      const int bo = baseB[nt] + kch * 32 + kq * 8;
      bH[nt] = *reinterpret_cast<const h8*>(inHi + bo);
      bL[nt] = *reinterpret_cast<const h8*>(inLo + bo);
    }
    #pragma unroll
    for (int mt = 0; mt < 2; ++mt)
      #pragma unroll
      for (int nt = 0; nt < 4; ++nt)
        acc[mt][nt] = MFMA16(aH[mt], bH[nt], acc[mt][nt]);
    #pragma unroll
    for (int mt = 0; mt < 2; ++mt)
      #pragma unroll
      for (int nt = 0; nt < 4; ++nt)
        acc[mt][nt] = MFMA16(aH[mt], bL[nt], acc[mt][nt]);
    #pragma unroll
    for (int mt = 0; mt < 2; ++mt)
      #pragma unroll
      for (int nt = 0; nt < 4; ++nt)
        acc[mt][nt] = MFMA16(aL[mt], bH[nt], acc[mt][nt]);
  }

  const int r4 = lane >> 4;
  #pragma unroll
  for (int mt = 0; mt < 2; ++mt) {
    const int co0 = cow + mt * 16 + r4 * 4;
    #pragma unroll
    for (int nt = 0; nt < 4; ++nt) {
      const int s = sblk + nt * 16 + c;
      if (s < 800)
        *reinterpret_cast<f4*>(part + ((long)tap * 800 + s) * 512 + co0) = acc[mt][nt];
    }
  }
}

// ---------------- rpn_finish: sum 9 taps + bias + relu -> rp512 CL ----------
__global__ __launch_bounds__(256)
void rpn_finish(const float* __restrict__ part, const float* __restrict__ bias,
                float* __restrict__ rp512) {
  const int t = blockIdx.x * 256 + threadIdx.x;
  if (t >= 800 * 128) return;
  const int co0 = (t % 128) * 4, s = t / 128;
  f4 acc = *reinterpret_cast<const f4*>(bias + co0);
  #pragma unroll
  for (int g = 0; g < 9; ++g)
    acc += *reinterpret_cast<const f4*>(part + ((long)g * 800 + s) * 512 + co0);
  f4 o;
  #pragma unroll
  for (int r = 0; r < 4; ++r) o[r] = fmaxf(acc[r], 0.f);
  *reinterpret_cast<f4*>(rp512 + (long)s * 512 + co0) = o;
}

// ---------------- 1x1 heads (fp32, CL input), straight to d_out --------------
__global__ __launch_bounds__(256)
void heads_kernel(const float* __restrict__ rp512,
                  const float* __restrict__ cls_w, const float* __restrict__ cls_b,
                  const float* __restrict__ reg_w, const float* __restrict__ reg_b,
                  float* __restrict__ out) {
  const int idx = blockIdx.x * 256 + threadIdx.x;
  if (idx >= 32 * 25 * 15) return;
  const int o = idx % 15, pix = (idx / 15) % 25, n = idx / 375;
  const float* __restrict__ ip = rp512 + ((long)(n * 25 + pix)) * 512;
  const float* __restrict__ wvp = (o < 3) ? (cls_w + o * 512) : (reg_w + (o - 3) * 512);
  float acc = 0.f;
  for (int k = 0; k < 512; k += 4) {
    const f4 a = *reinterpret_cast<const f4*>(ip + k);
    const f4 b = *reinterpret_cast<const f4*>(wvp + k);
    acc = fmaf(a[0], b[0], acc); acc = fmaf(a[1], b[1], acc);
    acc = fmaf(a[2], b[2], acc); acc = fmaf(a[3], b[3], acc);
  }
  if (o < 3) {
    acc += cls_b[o];
    out[OFF_CLS + n * 75 + o * 25 + pix] = 1.f / (1.f + expf(-acc));
  } else {
    acc += reg_b[o - 3];
    out[OFF_REG + n * 300 + (o - 3) * 25 + pix] = acc;
  }
}

// ---------------- FC: grid (32,20), float4 + wave reduce ---------------------
__global__ __launch_bounds__(256)
void fc_kernel(const float* __restrict__ feat, const float* __restrict__ fw,
               const float* __restrict__ fb, float* __restrict__ out) {
  const int n = blockIdx.x, j = blockIdx.y;
  const float* __restrict__ ip = feat + (long)n * 25088;
  const float* __restrict__ wj = fw + (long)j * 25088;
  float acc = 0.f;
  for (int k = threadIdx.x * 4; k < 25088; k += 1024) {
    const f4 a = *reinterpret_cast<const f4*>(ip + k);
    const f4 b = *reinterpret_cast<const f4*>(wj + k);
    acc = fmaf(a[0], b[0], acc); acc = fmaf(a[1], b[1], acc);
    acc = fmaf(a[2], b[2], acc); acc = fmaf(a[3], b[3], acc);
  }
  #pragma unroll
  for (int m = 32; m >= 1; m >>= 1) acc += __shfl_xor(acc, m, 64);
  __shared__ float red[4];
  const int wv = threadIdx.x >> 6;
  if ((threadIdx.x & 63) == 0) red[wv] = acc;
  __syncthreads();
  if (threadIdx.x == 0)
    out[OFF_LOGITS + n * 20 + j] = red[0] + red[1] + red[2] + red[3] + fb[j];
}

// ---------------- deparam bboxes + faithful buggy-IoU greedy NMS -------------
__global__ __launch_bounds__(128)
void bbox_nms_kernel(float* __restrict__ out) {
  const int n = blockIdx.x;
  const int t = threadIdx.x;
  __shared__ float bx0[75], by0[75], bx1[75], by1[75], area[75], sc[75];
  __shared__ int rank_s[75], order_s[75], keep_s[75];

  if (t < 75) {
    const int g1 = t / 15, g2 = (t / 3) % 5, a = t % 3;
    const float aw = (a == 0) ? 56.f : (a == 1 ? 112.f : 224.f);
    const float r0 = out[OFF_REG + n * 300 + 4 * t + 0];
    const float r1 = out[OFF_REG + n * 300 + 4 * t + 1];
    const float r2 = out[OFF_REG + n * 300 + 4 * t + 2];
    const float r3 = out[OFF_REG + n * 300 + 4 * t + 3];
    const float cx = r0 * aw + (float)g1;
    const float cy = r1 * aw + (float)g2;
    const float w_ = expf(r2) * aw;
    const float h_ = expf(r3) * aw;
    const float x0 = cx - 0.5f * w_, y0 = cy - 0.5f * h_;
    const float x1 = cx + 0.5f * w_, y1 = cy + 0.5f * h_;
    bx0[t] = x0; by0[t] = y0; bx1[t] = x1; by1[t] = y1;
    area[t] = (x1 - x0 + 1.f) * (y1 - y0 + 1.f);
    out[OFF_BOXES + n * 300 + 4 * t + 0] = x0;
    out[OFF_BOXES + n * 300 + 4 * t + 1] = y0;
    out[OFF_BOXES + n * 300 + 4 * t + 2] = x1;
    out[OFF_BOXES + n * 300 + 4 * t + 3] = y1;
    sc[t] = out[OFF_CLS + n * 75 + t];
    keep_s[t] = 1;
  }
  __syncthreads();
  if (t < 75) {
    const float si = sc[t];
    int rk = 0;
    for (int j = 0; j < 75; ++j) {
      const float sj = sc[j];
      rk += (sj > si) || (sj == si && j < t);
    }
    rank_s[t] = rk;
    order_s[rk] = t;
  }
  __syncthreads();
  for (int i = 0; i < 74; ++i) {
    if (keep_s[i]) {
      const int bi = order_s[i];
      if (t > i && t < 75) {
        const int bj = order_s[t];
        const float xA = fmaxf(bx0[bi], bx0[bj]);
        const float yA = fmaxf(by0[bi], by0[bj]);
        const float xB = fminf(bx1[bi], bx1[bj]);
        const float yB = fminf(by1[bi], by1[bj]);
        const float inter = fmaxf(0.f, xB - xA + 1.f) * fmaxf(0.f, yB - yA + 1.f);
        const float iou = inter / area[bi] + area[bj] - inter;  // faithful bug
        if (iou > 0.7f) keep_s[t] = 0;
      }
    }
    __syncthreads();
  }
  if (t < 75) out[OFF_KEEP + n * 75 + t] = keep_s[rank_s[t]] ? 1.f : 0.f;
}

// ------------------------------- launch --------------------------------------
extern "C" void kernel_launch(void* const* d_in, const int* in_sizes, int n_in,
                              void* d_out, int out_size, void* d_ws, size_t ws_size,
                              hipStream_t stream) {
  (void)in_sizes; (void)n_in; (void)out_size; (void)ws_size;
  const float* x     = (const float*)d_in[0];
  const float* fw0   = (const float*)d_in[1];
  const float* fb0   = (const float*)d_in[2];
  const float* fw1   = (const float*)d_in[3];
  const float* fb1   = (const float*)d_in[4];
  const float* fw2   = (const float*)d_in[5];
  const float* fb2   = (const float*)d_in[6];
  const float* fw3   = (const float*)d_in[7];
  const float* fb3   = (const float*)d_in[8];
  const float* fw4   = (const float*)d_in[9];
  const float* fb4   = (const float*)d_in[10];
  const float* rpw_w = (const float*)d_in[11];
  const float* rpw_b = (const float*)d_in[12];
  const float* cls_w = (const float*)d_in[13];
  const float* cls_b = (const float*)d_in[14];
  const float* reg_w = (const float*)d_in[15];
  const float* reg_b = (const float*)d_in[16];
  const float* fc_w  = (const float*)d_in[17];
  const float* fc_b  = (const float*)d_in[18];
  float* out = (float*)d_out;
  char* ws = (char*)d_ws;

  // activation buffers (fp16 hi/lo planes)
  _Float16* I0h = (_Float16*)(ws + A_OFF);
  _Float16* I0l = I0h + I0_E;
  _Float16* I1h = (_Float16*)(ws + B_OFF);
  _Float16* I1l = I1h + I1_E;
  _Float16* I2h = (_Float16*)(ws + A_OFF);
  _Float16* I2l = I2h + I2_E;
  _Float16* I3h = (_Float16*)(ws + B_OFF);
  _Float16* I3l = I3h + I3_E;
  _Float16* I4h = (_Float16*)(ws + A_OFF);
  _Float16* I4l = I4h + I4_E;
  float* feat  = (float*)(ws + A_OFF + (size_t)I4_E * 4);            // 3.2MB
  float* rp512 = (float*)(ws + A_OFF + (size_t)I4_E * 4 + 3211264);  // 1.6MB
  float* part  = (float*)(ws + P_OFF);                               // partials

  // converted weights [tap*kch][co][32] hi/lo
  _Float16* w1h = (_Float16*)(ws + W_OFF);                _Float16* w1l = w1h + 73728;
  _Float16* w2h = (_Float16*)(ws + W_OFF + 294912);       _Float16* w2l = w2h + 294912;
  _Float16* w3h = (_Float16*)(ws + W_OFF + 1474560);      _Float16* w3l = w3h + 1179648;
  _Float16* w4h = (_Float16*)(ws + W_OFF + 6193152);      _Float16* w4l = w4h + 2359296;
  _Float16* wrh = (_Float16*)(ws + W_OFF + 15630336);     _Float16* wrl = wrh + 2359296;

  // weight conversion
  wcvt<<<(73728 + 255) / 256, 256, 0, stream>>>(fw1, w1h, w1l, 128, 64);
  wcvt<<<(294912 + 255) / 256, 256, 0, stream>>>(fw2, w2h, w2l, 256, 128);
  wcvt<<<(1179648 + 255) / 256, 256, 0, stream>>>(fw3, w3h, w3l, 512, 256);
  wcvt<<<(2359296 + 255) / 256, 256, 0, stream>>>(fw4, w4h, w4l, 512, 512);
  wcvt<<<(2359296 + 255) / 256, 256, 0, stream>>>(rpw_w, wrh, wrl, 512, 512);

  // pad rings for I0, I1
  zero_ring<<<512, 256, 0, stream>>>(I0h, I0l, 114, 64);
  zero_ring<<<512, 256, 0, stream>>>(I1h, I1l, 58, 128);

  // L0 direct conv (LDS-staged coalesced output)
  conv_l0<<<32 * 49, 256, 0, stream>>>(x, fw0, fb0, I0h, I0l);

  // L1: 64->128 @112, tap-reuse row tiles, XH=2, co128 in-block, KPH=2
  convrow<64, 128, 112, 2, 2, 132, 136, 2><<<dim3(32 * 56 * 2, 1), 256, 0, stream>>>(
      I0h, I0l, w1h, w1l, fb1, I1h, I1l);
  zero_ring<<<512, 256, 0, stream>>>(I2h, I2l, 30, 256);   // I0 region now free
  // L2: 128->256 @56, tap-reuse rows, co-split x2, KPH=2
  convrow<128, 256, 56, 1, 2, 132, 136, 2><<<dim3(32 * 28, 2), 256, 0, stream>>>(
      I1h, I1l, w2h, w2l, fb2, I2h, I2l);
  zero_ring<<<512, 256, 0, stream>>>(I3h, I3l, 16, 512);   // I1 region now free
  // L3: 256->512 @28, tap-reuse rows, co256/block, co-split x2, KPH=2
  convrow<256, 512, 28, 1, 4, 68, 72, 2><<<dim3(32 * 14, 2), 256, 0, stream>>>(
      I2h, I2l, w3h, w3l, fb3, I3h, I3l);
  // L4: 512->512 @14, split-tap x3 -> partials, KPH=2, then finish
  convpool<512, 512, 14, 256, 64, 3, 2, 1><<<dim3(98, 2, 3), 256, 0, stream>>>(
      I3h, I3l, w4h, w4l, nullptr, nullptr, nullptr, part);
  l4_finish<<<(1568 * 128 + 255) / 256, 256, 0, stream>>>(part, fb4, I4h, I4l, feat);

  // RPN: split-tap x9 -> partials, then finish
  rpn_partial<<<dim3(13, 4, 9), 256, 0, stream>>>(I4h, I4l, wrh, wrl, part);
  rpn_finish<<<(800 * 128 + 255) / 256, 256, 0, stream>>>(part, rpw_b, rp512);

  heads_kernel<<<(12000 + 255) / 256, 256, 0, stream>>>(rp512, cls_w, cls_b, reg_w, reg_b, out);
  fc_kernel<<<dim3(32, 20), 256, 0, stream>>>(feat, fc_w, fc_b, out);
  bbox_nms_kernel<<<BATCH, 128, 0, stream>>>(out);
}

// Round 12
// 863.709 us; speedup vs baseline: 1.0084x; 1.0084x over previous
//
#include <hip/hip_runtime.h>
#include <math.h>

// VGG_RP round 12: convrow A-load pipeline fix. r11 diagnosis: each tap's
// A-loads were issued AFTER the next-group stage16 queue, so the A vmcnt-wait
// (in-order retirement) drained ~900cy of in-flight HBM staging at tap 0 and
// exposed ~300cy L2 latency per later tap -> predicted util 52% vs measured
// 45.7%. Fix: (1) group's first-tap A issued BEFORE stages (older than stages
// -> no drain), (2) one-tap-ahead A prefetch in the unrolled 6-tap loop
// (static a[2][4] dbuf). Scheduling-only: math/swizzle/sync identical to r11.
// All other kernels unchanged (r11 passed, 871us).
//
// d_out (float32), out_size = 24640:
//   [0,640) logits | [640,3040) rp_cls | [3040,12640) rp_reg
//   [12640,22240) bboxes | [22240,24640) keep

#define OFF_LOGITS 0
#define OFF_CLS    640
#define OFF_REG    3040
#define OFF_BOXES  12640
#define OFF_KEEP   22240

constexpr int BATCH = 32;

typedef _Float16 h8 __attribute__((ext_vector_type(8)));
typedef _Float16 h4 __attribute__((ext_vector_type(4)));
typedef float    f4 __attribute__((ext_vector_type(4)));

#define MFMA16(a, b, c) __builtin_amdgcn_mfma_f32_16x16x32_f16(a, b, c, 0, 0, 0)

#if defined(__has_builtin)
#  if __has_builtin(__builtin_amdgcn_global_load_lds)
#    define HAS_GLL 1
#  endif
#endif

// async global->LDS, 16B per lane. lbase must be wave-uniform (HW adds lane*16).
__device__ __forceinline__ void stage16(const _Float16* g, _Float16* lbase, int lane) {
#ifdef HAS_GLL
  __builtin_amdgcn_global_load_lds((const __attribute__((address_space(1))) void*)g,
                                   (__attribute__((address_space(3))) void*)lbase,
                                   16, 0, 0);
#else
  *reinterpret_cast<h8*>(lbase + lane * 8) = *reinterpret_cast<const h8*>(g);
#endif
}

// ---------------- workspace layout (bytes) ----------------
constexpr size_t A_OFF = 0;              // I0 -> I2 -> {I4, feat, rp512, partials}
constexpr size_t B_OFF = 106463232;      // I1 -> I3
constexpr size_t W_OFF = 161579008;      // converted weights
constexpr size_t P_OFF = A_OFF + 8388608;  // partials (overlay dead I2 region)

constexpr int I0_E = 26615808;   // 32*114*114*64
constexpr int I1_E = 13778944;   // 32*58*58*128
constexpr int I2_E = 7372800;    // 32*30*30*256
constexpr int I3_E = 4194304;    // 32*16*16*512
constexpr int I4_E = 802816;     // 32*7*7*512

// ---------------- weight convert: OIHW fp32 -> [tap*kch][co][32] hi/lo ------
__global__ __launch_bounds__(256)
void wcvt(const float* __restrict__ src, _Float16* __restrict__ dHi,
          _Float16* __restrict__ dLo, int COUT, int CIN) {
  const int total = COUT * CIN * 9;
  for (int idx = blockIdx.x * 256 + threadIdx.x; idx < total; idx += gridDim.x * 256) {
    const int co = idx / (CIN * 9);
    const int r = idx % (CIN * 9);
    const int ci = r / 9, tap = r % 9;
    const float v = src[idx];
    const _Float16 h = (_Float16)v;
    const int o = ((tap * (CIN >> 5) + (ci >> 5)) * COUT + co) * 32 + (ci & 31);
    dHi[o] = h;
    dLo[o] = (_Float16)(v - (float)h);
  }
}

// ---------------- zero the 1-px pad ring of a CL fp16 buffer ----------------
__global__ __launch_bounds__(256)
void zero_ring(_Float16* __restrict__ hi, _Float16* __restrict__ lo, int P, int C) {
  const int c8n = C / 8, cells = 4 * P - 4;
  const int tot = 32 * cells * c8n;
  for (int idx = blockIdx.x * 256 + threadIdx.x; idx < tot; idx += gridDim.x * 256) {
    const int c8 = idx % c8n;
    const int cell = (idx / c8n) % cells;
    const int n = idx / (c8n * cells);
    int y, xx;
    if (cell < 2 * P) { y = (cell < P) ? 0 : (P - 1); xx = cell % P; }
    else { const int q = cell - 2 * P; y = 1 + (q >> 1); xx = (q & 1) ? (P - 1) : 0; }
    const long o = ((long)(n * P + y) * P + xx) * C + c8 * 8;
    h8 z = {};
    *reinterpret_cast<h8*>(hi + o) = z;
    *reinterpret_cast<h8*>(lo + o) = z;
  }
}

// ---------------- L0: 3->64 direct fp32 conv+pool, LDS-staged output --------
constexpr int L0_SW   = 0;              // 1728 floats
constexpr int L0_SB   = 6912;           // 64 floats
constexpr int L0_SIN  = 7168;           // 3*34*34 floats (dead after win load)
constexpr int L0_HI   = 7168;           // 256 px * 144B (overlays sIn)
constexpr int L0_LO   = 7168 + 36864;   // 256 px * 144B
constexpr int L0_LDS  = 7168 + 73728;   // 80,896 B total

__global__ __launch_bounds__(256)
void conv_l0(const float* __restrict__ x, const float* __restrict__ w0,
             const float* __restrict__ b0, _Float16* __restrict__ outHi,
             _Float16* __restrict__ outLo) {
  const int bid = blockIdx.x;
  const int tx0 = (bid % 7) * 16, ty0 = ((bid / 7) % 7) * 16, n = bid / 49;
  __align__(16) __shared__ char lds[L0_LDS];
  float* sW = (float*)(lds + L0_SW);
  float* sB = (float*)(lds + L0_SB);
  float* sIn = (float*)(lds + L0_SIN);
  const int tid = threadIdx.x;
  for (int idx = tid; idx < 3 * 34 * 34; idx += 256) {
    const int ci = idx / 1156, rem = idx % 1156, r = rem / 34, cc = rem % 34;
    const int y = 2 * ty0 - 1 + r, xx = 2 * tx0 - 1 + cc;
    float v = 0.f;
    if ((unsigned)y < 224u && (unsigned)xx < 224u)
      v = x[((n * 3 + ci) * 224 + y) * 224 + xx];
    sIn[idx] = v;
  }
  for (int idx = tid; idx < 1728; idx += 256) sW[idx] = w0[idx];
  if (tid < 64) sB[tid] = b0[tid];
  __syncthreads();

  const int tpy = tid / 16, tpx = tid % 16;
  float win[3][4][4];
  #pragma unroll
  for (int ci = 0; ci < 3; ++ci)
    #pragma unroll
    for (int dr = 0; dr < 4; ++dr)
      #pragma unroll
      for (int dc = 0; dc < 4; ++dc)
        win[ci][dr][dc] = sIn[ci * 1156 + (2 * tpy + dr) * 34 + (2 * tpx + dc)];
  __syncthreads();  // all reads of sIn done before sOut overlays it

  for (int co4 = 0; co4 < 16; ++co4) {
    h4 hh, ll;
    #pragma unroll
    for (int j = 0; j < 4; ++j) {
      const int co = co4 * 4 + j;
      float a00 = 0.f, a01 = 0.f, a10 = 0.f, a11 = 0.f;
      #pragma unroll
      for (int ci = 0; ci < 3; ++ci)
        #pragma unroll
        for (int ky = 0; ky < 3; ++ky)
          #pragma unroll
          for (int kx = 0; kx < 3; ++kx) {
            const float wv = sW[co * 27 + ci * 9 + ky * 3 + kx];
            a00 = fmaf(win[ci][ky][kx], wv, a00);
            a01 = fmaf(win[ci][ky][kx + 1], wv, a01);
            a10 = fmaf(win[ci][ky + 1][kx], wv, a10);
            a11 = fmaf(win[ci][ky + 1][kx + 1], wv, a11);
          }
      const float p = fmaxf(fmaxf(fmaxf(a00, a01), fmaxf(a10, a11)) + sB[co], 0.f);
      const _Float16 h = (_Float16)p;
      hh[j] = h;
      ll[j] = (_Float16)(p - (float)h);
    }
    *reinterpret_cast<h4*>(lds + L0_HI + tid * 144 + co4 * 8) = hh;
    *reinterpret_cast<h4*>(lds + L0_LO + tid * 144 + co4 * 8) = ll;
  }
  __syncthreads();

  const int tr_half = tid >> 7;
  const int pixrow = (tid & 127) >> 3;
  const int ch8 = (tid & 7) * 8;
  #pragma unroll
  for (int i = 0; i < 8; ++i) {
    const int tr = 2 * i + tr_half;
    const int pix = tr * 16 + pixrow;
    const long ga = ((long)(n * 114 + ty0 + tr + 1) * 114 + tx0 + pixrow + 1) * 64 + ch8;
    *reinterpret_cast<h8*>(outHi + ga) =
        *reinterpret_cast<const h8*>(lds + L0_HI + pix * 144 + ch8 * 2);
    *reinterpret_cast<h8*>(outLo + ga) =
        *reinterpret_cast<const h8*>(lds + L0_LO + pix * 144 + ch8 * 2);
  }
}

// ---------------- convrow: tap-reuse row-tile conv+pool (L1/L2/L3) ----------
// Block = (n, py, xh) x co-split blockIdx.y. Stages STG rows per kc-chunk,
// KPH chunks per phase; kx taps read the same staged tile at +2*kx.
// A-load pipeline: first tap's A issued BEFORE the stage block (its wait
// doesn't drain the staging queue); subsequent taps prefetched one ahead.
template<int CIN, int COUT, int H, int XH, int NCOW, int STG, int SARR, int KPH>
__global__ __launch_bounds__(256, 2)
void convrow(const _Float16* __restrict__ inHi, const _Float16* __restrict__ inLo,
             const _Float16* __restrict__ wHi, const _Float16* __restrict__ wLo,
             const float* __restrict__ bias, _Float16* __restrict__ outHi,
             _Float16* __restrict__ outLo) {
  constexpr int W = H, Hp = H / 2, Wp = W / 2, PW = W + 2, POW = Wp + 2;
  constexpr int KCH = CIN / 32;
  constexpr int NCH = 3 * KCH;         // (ky, kc) chunks
  constexpr int NGRP = NCH / KPH;      // barrier groups
  static_assert(NCH % KPH == 0, "even groups");
  constexpr int NTAP = KPH * 3;        // taps per group
  constexpr int NSPW = 4 / NCOW;       // sp waves
  constexpr int NFULL = STG / 64;      // full staging rounds
  constexpr int TAIL = STG % 64;       // tail rows (staged by tid < TAIL*4)
  constexpr int TSZ = SARR * 32;       // elements per (hl, j) tile
  static_assert(NSPW * 64 + 3 < STG + 1, "staged rows cover shifted reads");
  __align__(16) __shared__ _Float16 sB[2][2][KPH][TSZ];

  const int tid = threadIdx.x;
  const int lane = tid & 63, wv = tid >> 6;
  const int c = lane & 15, kq = lane >> 4;
  const int cow = blockIdx.y * (NCOW * 64) + (wv % NCOW) * 64;
  const int spl = (wv / NCOW) * 64;
  const int xh = blockIdx.x % XH;
  const int pyn = blockIdx.x / XH;
  const int py = pyn % Hp, n = pyn / Hp;
  const int x0 = xh * 64;

  // staging sources (ky=0,kc=0 base; per-chunk add ky*PW*CIN + kc*32)
  int gstage[NFULL + 1];
  #pragma unroll
  for (int i = 0; i < NFULL + 1; ++i) {
    const int sl = i * 64 + tid / 4;
    const int ry = sl & 1;
    int xx = x0 + (sl >> 1);
    if (xx > PW - 1) xx = PW - 1;      // clamp into right zero-pad col
    gstage[i] = ((n * (H + 2) + 2 * py + ry) * PW + xx) * CIN +
                (((tid & 3) ^ ((sl >> 1) & 3)) * 8);
  }
  // ds_read offsets per (kx, nt), swizzled
  int dsoff[3][4];
  #pragma unroll
  for (int kx = 0; kx < 3; ++kx)
    #pragma unroll
    for (int nt = 0; nt < 4; ++nt) {
      const int r = spl + nt * 16 + c + 2 * kx;
      dsoff[kx][nt] = r * 32 + ((kq ^ ((r >> 1) & 3)) * 8);
    }

  // prologue: stage group 0 (KPH chunks) into buf 0
  #pragma unroll
  for (int j = 0; j < KPH; ++j) {
    const int tb = (j / KCH) * PW * CIN + (j % KCH) * 32;
    #pragma unroll
    for (int i = 0; i < NFULL; ++i) {
      stage16(inHi + gstage[i] + tb, &sB[0][0][j][i * 2048 + wv * 512], lane);
      stage16(inLo + gstage[i] + tb, &sB[0][1][j][i * 2048 + wv * 512], lane);
    }
    if (TAIL && tid < TAIL * 4) {
      stage16(inHi + gstage[NFULL] + tb, &sB[0][0][j][NFULL * 2048], lane);
      stage16(inLo + gstage[NFULL] + tb, &sB[0][1][j][NFULL * 2048], lane);
    }
  }
  __syncthreads();

  f4 acc[4][4] = {};
  int cur = 0;
  for (int g = 0; g < NGRP; ++g) {
    h8 aH[2][4], aL[2][4];
    // A for first tap of this group — issued BEFORE the stage block so its
    // vmcnt-wait (older than stages) never drains the staging queue.
    {
      const int ch = g * KPH;
      const int ky = ch / KCH, kc = ch % KCH;
      const long abase = ((long)((ky * 3 + 0) * KCH + kc) * COUT + cow) * 32;
      #pragma unroll
      for (int mt = 0; mt < 4; ++mt) {
        const long ao = abase + (mt * 16 + c) * 32 + kq * 8;
        aH[0][mt] = *reinterpret_cast<const h8*>(wHi + ao);
        aL[0][mt] = *reinterpret_cast<const h8*>(wLo + ao);
      }
    }
    __builtin_amdgcn_sched_barrier(0);
    // stage next group into the other buffer (drains at the barrier)
    if (g + 1 < NGRP) {
      #pragma unroll
      for (int j2 = 0; j2 < KPH; ++j2) {
        const int ch2 = (g + 1) * KPH + j2;
        const int tb2 = (ch2 / KCH) * PW * CIN + (ch2 % KCH) * 32;
        #pragma unroll
        for (int i = 0; i < NFULL; ++i) {
          stage16(inHi + gstage[i] + tb2,
                  &sB[cur ^ 1][0][j2][i * 2048 + wv * 512], lane);
          stage16(inLo + gstage[i] + tb2,
                  &sB[cur ^ 1][1][j2][i * 2048 + wv * 512], lane);
        }
        if (TAIL && tid < TAIL * 4) {
          stage16(inHi + gstage[NFULL] + tb2, &sB[cur ^ 1][0][j2][NFULL * 2048], lane);
          stage16(inLo + gstage[NFULL] + tb2, &sB[cur ^ 1][1][j2][NFULL * 2048], lane);
        }
      }
    }
    __builtin_amdgcn_sched_barrier(0);
    // compute NTAP taps; prefetch tap t+1's A during tap t's MFMAs
    #pragma unroll
    for (int t = 0; t < NTAP; ++t) {
      const int j = t / 3, kx = t % 3;
      // prefetch next tap's A into the other static buffer (t compile-time)
      if (t + 1 < NTAP) {
        const int t2 = t + 1;
        const int j2 = t2 / 3, kx2 = t2 % 3;
        const int ch2 = g * KPH + j2;
        const int ky2 = ch2 / KCH, kc2 = ch2 % KCH;
        const long abase2 = ((long)((ky2 * 3 + kx2) * KCH + kc2) * COUT + cow) * 32;
        #pragma unroll
        for (int mt = 0; mt < 4; ++mt) {
          const long ao = abase2 + (mt * 16 + c) * 32 + kq * 8;
          aH[t2 & 1][mt] = *reinterpret_cast<const h8*>(wHi + ao);
          aL[t2 & 1][mt] = *reinterpret_cast<const h8*>(wLo + ao);
        }
      }
      __builtin_amdgcn_sched_barrier(0);
      h8 bH[4], bL[4];
      #pragma unroll
      for (int nt = 0; nt < 4; ++nt) {
        bH[nt] = *reinterpret_cast<const h8*>(&sB[cur][0][j][dsoff[kx][nt]]);
        bL[nt] = *reinterpret_cast<const h8*>(&sB[cur][1][j][dsoff[kx][nt]]);
      }
      __builtin_amdgcn_s_setprio(1);
      #pragma unroll
      for (int mt = 0; mt < 4; ++mt)
        #pragma unroll
        for (int nt = 0; nt < 4; ++nt)
          acc[mt][nt] = MFMA16(aH[t & 1][mt], bH[nt], acc[mt][nt]);
      #pragma unroll
      for (int mt = 0; mt < 4; ++mt)
        #pragma unroll
        for (int nt = 0; nt < 4; ++nt)
          acc[mt][nt] = MFMA16(aH[t & 1][mt], bL[nt], acc[mt][nt]);
      #pragma unroll
      for (int mt = 0; mt < 4; ++mt)
        #pragma unroll
        for (int nt = 0; nt < 4; ++nt)
          acc[mt][nt] = MFMA16(aL[t & 1][mt], bH[nt], acc[mt][nt]);
      __builtin_amdgcn_s_setprio(0);
      __builtin_amdgcn_sched_barrier(0);
    }
    __syncthreads();
    cur ^= 1;
  }

  // epilogue: 2x2 pool, bias+relu, guarded padded-CL write
  const int r4 = lane >> 4;
  #pragma unroll
  for (int mt = 0; mt < 4; ++mt) {
    const int co0 = cow + mt * 16 + r4 * 4;
    const f4 bi = *reinterpret_cast<const f4*>(bias + co0);
    #pragma unroll
    for (int nt = 0; nt < 4; ++nt) {
      f4 v = acc[mt][nt];
      #pragma unroll
      for (int r = 0; r < 4; ++r) {
        const float m1 = fmaxf(v[r], __shfl_xor(v[r], 1, 64));
        v[r] = fmaxf(m1, __shfl_xor(m1, 2, 64));
      }
      if ((lane & 3) == 0) {
        const int rr = spl + nt * 16 + c;
        const int pxg = xh * 32 + (rr >> 2);
        if (pxg < Wp) {
          h4 hh, ll;
          #pragma unroll
          for (int r = 0; r < 4; ++r) {
            const float p = fmaxf(v[r] + bi[r], 0.f);
            const _Float16 h = (_Float16)p;
            hh[r] = h;
            ll[r] = (_Float16)(p - (float)h);
          }
          const long oa = ((long)((n * (Hp + 2) + py + 1) * POW + pxg + 1)) * COUT + co0;
          *reinterpret_cast<h4*>(outHi + oa) = hh;
          *reinterpret_cast<h4*>(outLo + oa) = ll;
        }
      }
    }
  }
}

// ---------------- convpool: r8 3-buffer counted pipeline (L4 split-tap) -----
template<int CIN, int COUT, int H, int BCO, int BSP, int TG, int KPH, int MODE>
__global__ __launch_bounds__(256, 2)
void convpool(const _Float16* __restrict__ inHi, const _Float16* __restrict__ inLo,
              const _Float16* __restrict__ wHi, const _Float16* __restrict__ wLo,
              const float* __restrict__ bias, _Float16* __restrict__ outHi,
              _Float16* __restrict__ outLo, float* __restrict__ outF) {
  constexpr int W = H, Hp = H / 2, Wp = W / 2, PW = W + 2, POW = Wp + 2;
  constexpr int NCOW = BCO / 64, NSPW = BSP / 64;
  static_assert(NCOW * NSPW == 4, "4 waves");
  constexpr int KCH = CIN / 32;
  constexpr int NCH = TG * KCH;
  constexpr int NPH = NCH / KPH;
  static_assert(NCH % KPH == 0, "even phases");
  static_assert(KPH * 2 * (BSP / 64) == 4, "prologue vmcnt literal = 4");
  constexpr int NISS = BSP / 64;
  constexpr int SPTOT = 32 * H * W;
  constexpr int TSZ = BSP * 32;
  __align__(16) __shared__ _Float16 sB[3 * 2 * KPH * TSZ];
  #define TIDX(buf, hl, j) ((((buf) * 2 + (hl)) * KPH + (j)) * TSZ)

  const int tid = threadIdx.x;
  const int lane = tid & 63, wv = tid >> 6;
  const int c = lane & 15, kq = lane >> 4;
  const int cow = blockIdx.y * BCO + (wv % NCOW) * 64;
  const int spl = (wv / NCOW) * 64;
  const int sblk = blockIdx.x * BSP;
  const int tap0 = (TG == 9) ? 0 : blockIdx.z * TG;

  int gstage[NISS];
  #pragma unroll
  for (int i = 0; i < NISS; ++i) {
    const int sl = i * 64 + tid / 4;
    const int sg = sblk + sl;
    const int ry = sg & 1, tt = sg >> 1;
    const int x = tt % W, u = tt / W;
    const int py = u % Hp, n = u / Hp;
    gstage[i] = ((n * (H + 2) + 2 * py + ry) * PW + x) * CIN +
                (((tid & 3) ^ ((sl >> 1) & 3)) * 8);
  }
  int dsoff[4];
  #pragma unroll
  for (int nt = 0; nt < 4; ++nt) {
    const int row = spl + nt * 16 + c;
    dsoff[nt] = row * 32 + ((kq ^ ((row >> 1) & 3)) * 8);
  }

  #pragma unroll
  for (int pp = 0; pp < 2; ++pp) {
    #pragma unroll
    for (int j = 0; j < KPH; ++j) {
      const int ch = pp * KPH + j;
      const int tap = tap0 + ch / KCH, kc = ch % KCH;
      const int tb = ((tap / 3) * PW + (tap % 3)) * CIN + kc * 32;
      #pragma unroll
      for (int i = 0; i < NISS; ++i) {
        stage16(inHi + gstage[i] + tb, &sB[TIDX(pp, 0, j) + i * 2048 + wv * 512], lane);
        stage16(inLo + gstage[i] + tb, &sB[TIDX(pp, 1, j) + i * 2048 + wv * 512], lane);
      }
    }
  }
  __builtin_amdgcn_sched_barrier(0);
  asm volatile("s_waitcnt vmcnt(4)" ::: "memory");
  __builtin_amdgcn_sched_barrier(0);
  __builtin_amdgcn_s_barrier();
  __builtin_amdgcn_sched_barrier(0);

  f4 acc[4][4] = {};
  for (int ph = 0; ph < NPH; ++ph) {
    const int bp = ph % 3;
    h8 aH[KPH][4], aL[KPH][4];
    #pragma unroll
    for (int j = 0; j < KPH; ++j) {
      const int ch = ph * KPH + j;
      const int tap = tap0 + ch / KCH;
      const int kc = ch % KCH;
      const long abase = ((long)(tap * KCH + kc) * COUT + cow) * 32;
      #pragma unroll
      for (int mt = 0; mt < 4; ++mt) {
        const long ao = abase + (mt * 16 + c) * 32 + kq * 8;
        aH[j][mt] = *reinterpret_cast<const h8*>(wHi + ao);
        aL[j][mt] = *reinterpret_cast<const h8*>(wLo + ao);
      }
    }
    __builtin_amdgcn_sched_barrier(0);
    if (ph + 2 < NPH) {
      const int bs = (ph + 2) % 3;
      #pragma unroll
      for (int j2 = 0; j2 < KPH; ++j2) {
        const int ch2 = (ph + 2) * KPH + j2;
        const int tap2 = tap0 + ch2 / KCH;
        const int tb2 = ((tap2 / 3) * PW + (tap2 % 3)) * CIN + (ch2 % KCH) * 32;
        #pragma unroll
        for (int i = 0; i < NISS; ++i) {
          stage16(inHi + gstage[i] + tb2,
                  &sB[TIDX(bs, 0, j2) + i * 2048 + wv * 512], lane);
          stage16(inLo + gstage[i] + tb2,
                  &sB[TIDX(bs, 1, j2) + i * 2048 + wv * 512], lane);
        }
      }
    }
    __builtin_amdgcn_sched_barrier(0);
    #pragma unroll
    for (int j = 0; j < KPH; ++j) {
      h8 bH[4], bL[4];
      #pragma unroll
      for (int nt = 0; nt < 4; ++nt) {
        bH[nt] = *reinterpret_cast<const h8*>(&sB[TIDX(bp, 0, j) + dsoff[nt]]);
        bL[nt] = *reinterpret_cast<const h8*>(&sB[TIDX(bp, 1, j) + dsoff[nt]]);
      }
      __builtin_amdgcn_s_setprio(1);
      #pragma unroll
      for (int mt = 0; mt < 4; ++mt)
        #pragma unroll
        for (int nt = 0; nt < 4; ++nt)
          acc[mt][nt] = MFMA16(aH[j][mt], bH[nt], acc[mt][nt]);
      #pragma unroll
      for (int mt = 0; mt < 4; ++mt)
        #pragma unroll
        for (int nt = 0; nt < 4; ++nt)
          acc[mt][nt] = MFMA16(aH[j][mt], bL[nt], acc[mt][nt]);
      #pragma unroll
      for (int mt = 0; mt < 4; ++mt)
        #pragma unroll
        for (int nt = 0; nt < 4; ++nt)
          acc[mt][nt] = MFMA16(aL[j][mt], bH[nt], acc[mt][nt]);
      __builtin_amdgcn_s_setprio(0);
    }
    __builtin_amdgcn_sched_barrier(0);
    __builtin_amdgcn_s_barrier();
    __builtin_amdgcn_sched_barrier(0);
  }
  #undef TIDX

  const int r4 = lane >> 4;
  if (MODE == 1) {
    #pragma unroll
    for (int mt = 0; mt < 4; ++mt) {
      const int co0 = cow + mt * 16 + r4 * 4;
      #pragma unroll
      for (int nt = 0; nt < 4; ++nt) {
        const int s = sblk + spl + nt * 16 + c;
        *reinterpret_cast<f4*>(outF + ((long)blockIdx.z * SPTOT + s) * COUT + co0) =
            acc[mt][nt];
      }
    }
  } else {
    #pragma unroll
    for (int mt = 0; mt < 4; ++mt) {
      const int co0 = cow + mt * 16 + r4 * 4;
      const f4 bi = *reinterpret_cast<const f4*>(bias + co0);
      #pragma unroll
      for (int nt = 0; nt < 4; ++nt) {
        f4 v = acc[mt][nt];
        #pragma unroll
        for (int r = 0; r < 4; ++r) {
          const float m1 = fmaxf(v[r], __shfl_xor(v[r], 1, 64));
          v[r] = fmaxf(m1, __shfl_xor(m1, 2, 64));
        }
        if ((lane & 3) == 0) {
          const int s = sblk + spl + nt * 16 + c;
          const int ps = s >> 2;
          const int n = ps / (Hp * Wp), rem = ps % (Hp * Wp);
          const int py = rem / Wp, px = rem % Wp;
          h4 hh, ll;
          #pragma unroll
          for (int r = 0; r < 4; ++r) {
            const float p = fmaxf(v[r] + bi[r], 0.f);
            const _Float16 h = (_Float16)p;
            hh[r] = h;
            ll[r] = (_Float16)(p - (float)h);
          }
          const long oa = ((long)((n * (Hp + 2) + py + 1) * POW + px + 1)) * COUT + co0;
          *reinterpret_cast<h4*>(outHi + oa) = hh;
          *reinterpret_cast<h4*>(outLo + oa) = ll;
        }
      }
    }
  }
}

// ---------------- l4_finish: sum 3 partials, pool, bias, relu ---------------
__global__ __launch_bounds__(256)
void l4_finish(const float* __restrict__ part, const float* __restrict__ bias,
               _Float16* __restrict__ I4h, _Float16* __restrict__ I4l,
               float* __restrict__ feat) {
  const int t = blockIdx.x * 256 + threadIdx.x;
  if (t >= 1568 * 128) return;
  const int co0 = (t % 128) * 4, p = t / 128;
  f4 m;
  #pragma unroll
  for (int q = 0; q < 4; ++q) {
    const long s = 4L * p + q;
    f4 v = *reinterpret_cast<const f4*>(part + s * 512 + co0);
    v += *reinterpret_cast<const f4*>(part + (6272 + s) * 512 + co0);
    v += *reinterpret_cast<const f4*>(part + (12544 + s) * 512 + co0);
    if (q == 0) m = v;
    else {
      #pragma unroll
      for (int r = 0; r < 4; ++r) m[r] = fmaxf(m[r], v[r]);
    }
  }
  const f4 bi = *reinterpret_cast<const f4*>(bias + co0);
  h4 hh, ll;
  const int n = p / 49, pix = p % 49;
  #pragma unroll
  for (int r = 0; r < 4; ++r) {
    const float pv = fmaxf(m[r] + bi[r], 0.f);
    const _Float16 h = (_Float16)pv;
    hh[r] = h;
    ll[r] = (_Float16)(pv - (float)h);
    feat[((long)(n * 512 + co0 + r)) * 49 + pix] = pv;
  }
  *reinterpret_cast<h4*>(I4h + (long)p * 512 + co0) = hh;
  *reinterpret_cast<h4*>(I4l + (long)p * 512 + co0) = ll;
}

// ---------------- RPN partial: one tap per blockIdx.z, K=512 GEMM -----------
__global__ __launch_bounds__(256)
void rpn_partial(const _Float16* __restrict__ inHi, const _Float16* __restrict__ inLo,
                 const _Float16* __restrict__ wHi, const _Float16* __restrict__ wLo,
                 float* __restrict__ part) {
  const int lane = threadIdx.x & 63, wv = threadIdx.x >> 6;
  const int cow = blockIdx.y * 128 + wv * 32;
  const int sblk = blockIdx.x * 64;
  const int tap = blockIdx.z, ky = tap / 3, kx = tap % 3;
  const int c = lane & 15, kq = lane >> 4;

  int baseB[4];
  #pragma unroll
  for (int nt = 0; nt < 4; ++nt) {
    int s = sblk + nt * 16 + c;
    if (s > 799) s = 799;
    const int n = s / 25, pix = s % 25, py = pix / 5, px = pix % 5;
    baseB[nt] = ((n * 7 + py + ky) * 7 + px + kx) * 512;
  }

  f4 acc[2][4] = {};
  for (int kch = 0; kch < 16; ++kch) {
    h8 aH[2], aL[2], bH[4], bL[4];
    const long abase = ((long)(tap * 16 + kch) * 512 + cow) * 32;
    #pragma unroll
    for (int mt = 0; mt < 2; ++mt) {
      const long ao = abase + (mt * 16 + c) * 32 + kq * 8;
      aH[mt] = *reinterpret_cast<const h8*>(wHi + ao);
      aL[mt] = *reinterpret_cast<const h8*>(wLo + ao);
    }
    #pragma unroll
    for (int nt = 0; nt < 4; ++nt) {
      const int bo = baseB[nt] + kch * 32 + kq * 8;
      bH[nt] = *reinterpret_cast<const h8*>(inHi + bo);
      bL[nt] = *reinterpret_cast<const h8*>(inLo + bo);
    }
    #pragma unroll
    for (int mt = 0; mt < 2; ++mt)
      #pragma unroll
      for (int nt = 0; nt < 4; ++nt)
        acc[mt][nt] = MFMA16(aH[mt], bH[nt], acc[mt][nt]);
    #pragma unroll
    for (int mt = 0; mt < 2; ++mt)
      #pragma unroll
      for (int nt = 0; nt < 4; ++nt)
        acc[mt][nt] = MFMA16(aH[mt], bL[nt], acc[mt][nt]);
    #pragma unroll
    for (int mt = 0; mt < 2; ++mt)
      #pragma unroll
      for (int nt = 0; nt < 4; ++nt)
        acc[mt][nt] = MFMA16(aL[mt], bH[nt], acc[mt][nt]);
  }

  const int r4 = lane >> 4;
  #pragma unroll
  for (int mt = 0; mt < 2; ++mt) {
    const int co0 = cow + mt * 16 + r4 * 4;
    #pragma unroll
    for (int nt = 0; nt < 4; ++nt) {
      const int s = sblk + nt * 16 + c;
      if (s < 800)
        *reinterpret_cast<f4*>(part + ((long)tap * 800 + s) * 512 + co0) = acc[mt][nt];
    }
  }
}

// ---------------- rpn_finish: sum 9 taps + bias + relu -> rp512 CL ----------
__global__ __launch_bounds__(256)
void rpn_finish(const float* __restrict__ part, const float* __restrict__ bias,
                float* __restrict__ rp512) {
  const int t = blockIdx.x * 256 + threadIdx.x;
  if (t >= 800 * 128) return;
  const int co0 = (t % 128) * 4, s = t / 128;
  f4 acc = *reinterpret_cast<const f4*>(bias + co0);
  #pragma unroll
  for (int g = 0; g < 9; ++g)
    acc += *reinterpret_cast<const f4*>(part + ((long)g * 800 + s) * 512 + co0);
  f4 o;
  #pragma unroll
  for (int r = 0; r < 4; ++r) o[r] = fmaxf(acc[r], 0.f);
  *reinterpret_cast<f4*>(rp512 + (long)s * 512 + co0) = o;
}

// ---------------- 1x1 heads (fp32, CL input), straight to d_out --------------
__global__ __launch_bounds__(256)
void heads_kernel(const float* __restrict__ rp512,
                  const float* __restrict__ cls_w, const float* __restrict__ cls_b,
                  const float* __restrict__ reg_w, const float* __restrict__ reg_b,
                  float* __restrict__ out) {
  const int idx = blockIdx.x * 256 + threadIdx.x;
  if (idx >= 32 * 25 * 15) return;
  const int o = idx % 15, pix = (idx / 15) % 25, n = idx / 375;
  const float* __restrict__ ip = rp512 + ((long)(n * 25 + pix)) * 512;
  const float* __restrict__ wvp = (o < 3) ? (cls_w + o * 512) : (reg_w + (o - 3) * 512);
  float acc = 0.f;
  for (int k = 0; k < 512; k += 4) {
    const f4 a = *reinterpret_cast<const f4*>(ip + k);
    const f4 b = *reinterpret_cast<const f4*>(wvp + k);
    acc = fmaf(a[0], b[0], acc); acc = fmaf(a[1], b[1], acc);
    acc = fmaf(a[2], b[2], acc); acc = fmaf(a[3], b[3], acc);
  }
  if (o < 3) {
    acc += cls_b[o];
    out[OFF_CLS + n * 75 + o * 25 + pix] = 1.f / (1.f + expf(-acc));
  } else {
    acc += reg_b[o - 3];
    out[OFF_REG + n * 300 + (o - 3) * 25 + pix] = acc;
  }
}

// ---------------- FC: grid (32,20), float4 + wave reduce ---------------------
__global__ __launch_bounds__(256)
void fc_kernel(const float* __restrict__ feat, const float* __restrict__ fw,
               const float* __restrict__ fb, float* __restrict__ out) {
  const int n = blockIdx.x, j = blockIdx.y;
  const float* __restrict__ ip = feat + (long)n * 25088;
  const float* __restrict__ wj = fw + (long)j * 25088;
  float acc = 0.f;
  for (int k = threadIdx.x * 4; k < 25088; k += 1024) {
    const f4 a = *reinterpret_cast<const f4*>(ip + k);
    const f4 b = *reinterpret_cast<const f4*>(wj + k);
    acc = fmaf(a[0], b[0], acc); acc = fmaf(a[1], b[1], acc);
    acc = fmaf(a[2], b[2], acc); acc = fmaf(a[3], b[3], acc);
  }
  #pragma unroll
  for (int m = 32; m >= 1; m >>= 1) acc += __shfl_xor(acc, m, 64);
  __shared__ float red[4];
  const int wv = threadIdx.x >> 6;
  if ((threadIdx.x & 63) == 0) red[wv] = acc;
  __syncthreads();
  if (threadIdx.x == 0)
    out[OFF_LOGITS + n * 20 + j] = red[0] + red[1] + red[2] + red[3] + fb[j];
}

// ---------------- deparam bboxes + faithful buggy-IoU greedy NMS -------------
__global__ __launch_bounds__(128)
void bbox_nms_kernel(float* __restrict__ out) {
  const int n = blockIdx.x;
  const int t = threadIdx.x;
  __shared__ float bx0[75], by0[75], bx1[75], by1[75], area[75], sc[75];
  __shared__ int rank_s[75], order_s[75], keep_s[75];

  if (t < 75) {
    const int g1 = t / 15, g2 = (t / 3) % 5, a = t % 3;
    const float aw = (a == 0) ? 56.f : (a == 1 ? 112.f : 224.f);
    const float r0 = out[OFF_REG + n * 300 + 4 * t + 0];
    const float r1 = out[OFF_REG + n * 300 + 4 * t + 1];
    const float r2 = out[OFF_REG + n * 300 + 4 * t + 2];
    const float r3 = out[OFF_REG + n * 300 + 4 * t + 3];
    const float cx = r0 * aw + (float)g1;
    const float cy = r1 * aw + (float)g2;
    const float w_ = expf(r2) * aw;
    const float h_ = expf(r3) * aw;
    const float x0 = cx - 0.5f * w_, y0 = cy - 0.5f * h_;
    const float x1 = cx + 0.5f * w_, y1 = cy + 0.5f * h_;
    bx0[t] = x0; by0[t] = y0; bx1[t] = x1; by1[t] = y1;
    area[t] = (x1 - x0 + 1.f) * (y1 - y0 + 1.f);
    out[OFF_BOXES + n * 300 + 4 * t + 0] = x0;
    out[OFF_BOXES + n * 300 + 4 * t + 1] = y0;
    out[OFF_BOXES + n * 300 + 4 * t + 2] = x1;
    out[OFF_BOXES + n * 300 + 4 * t + 3] = y1;
    sc[t] = out[OFF_CLS + n * 75 + t];
    keep_s[t] = 1;
  }
  __syncthreads();
  if (t < 75) {
    const float si = sc[t];
    int rk = 0;
    for (int j = 0; j < 75; ++j) {
      const float sj = sc[j];
      rk += (sj > si) || (sj == si && j < t);
    }
    rank_s[t] = rk;
    order_s[rk] = t;
  }
  __syncthreads();
  for (int i = 0; i < 74; ++i) {
    if (keep_s[i]) {
      const int bi = order_s[i];
      if (t > i && t < 75) {
        const int bj = order_s[t];
        const float xA = fmaxf(bx0[bi], bx0[bj]);
        const float yA = fmaxf(by0[bi], by0[bj]);
        const float xB = fminf(bx1[bi], bx1[bj]);
        const float yB = fminf(by1[bi], by1[bj]);
        const float inter = fmaxf(0.f, xB - xA + 1.f) * fmaxf(0.f, yB - yA + 1.f);
        const float iou = inter / area[bi] + area[bj] - inter;  // faithful bug
        if (iou > 0.7f) keep_s[t] = 0;
      }
    }
    __syncthreads();
  }
  if (t < 75) out[OFF_KEEP + n * 75 + t] = keep_s[rank_s[t]] ? 1.f : 0.f;
}

// ------------------------------- launch --------------------------------------
extern "C" void kernel_launch(void* const* d_in, const int* in_sizes, int n_in,
                              void* d_out, int out_size, void* d_ws, size_t ws_size,
                              hipStream_t stream) {
  (void)in_sizes; (void)n_in; (void)out_size; (void)ws_size;
  const float* x     = (const float*)d_in[0];
  const float* fw0   = (const float*)d_in[1];
  const float* fb0   = (const float*)d_in[2];
  const float* fw1   = (const float*)d_in[3];
  const float* fb1   = (const float*)d_in[4];
  const float* fw2   = (const float*)d_in[5];
  const float* fb2   = (const float*)d_in[6];
  const float* fw3   = (const float*)d_in[7];
  const float* fb3   = (const float*)d_in[8];
  const float* fw4   = (const float*)d_in[9];
  const float* fb4   = (const float*)d_in[10];
  const float* rpw_w = (const float*)d_in[11];
  const float* rpw_b = (const float*)d_in[12];
  const float* cls_w = (const float*)d_in[13];
  const float* cls_b = (const float*)d_in[14];
  const float* reg_w = (const float*)d_in[15];
  const float* reg_b = (const float*)d_in[16];
  const float* fc_w  = (const float*)d_in[17];
  const float* fc_b  = (const float*)d_in[18];
  float* out = (float*)d_out;
  char* ws = (char*)d_ws;

  // activation buffers (fp16 hi/lo planes)
  _Float16* I0h = (_Float16*)(ws + A_OFF);
  _Float16* I0l = I0h + I0_E;
  _Float16* I1h = (_Float16*)(ws + B_OFF);
  _Float16* I1l = I1h + I1_E;
  _Float16* I2h = (_Float16*)(ws + A_OFF);
  _Float16* I2l = I2h + I2_E;
  _Float16* I3h = (_Float16*)(ws + B_OFF);
  _Float16* I3l = I3h + I3_E;
  _Float16* I4h = (_Float16*)(ws + A_OFF);
  _Float16* I4l = I4h + I4_E;
  float* feat  = (float*)(ws + A_OFF + (size_t)I4_E * 4);            // 3.2MB
  float* rp512 = (float*)(ws + A_OFF + (size_t)I4_E * 4 + 3211264);  // 1.6MB
  float* part  = (float*)(ws + P_OFF);                               // partials

  // converted weights [tap*kch][co][32] hi/lo
  _Float16* w1h = (_Float16*)(ws + W_OFF);                _Float16* w1l = w1h + 73728;
  _Float16* w2h = (_Float16*)(ws + W_OFF + 294912);       _Float16* w2l = w2h + 294912;
  _Float16* w3h = (_Float16*)(ws + W_OFF + 1474560);      _Float16* w3l = w3h + 1179648;
  _Float16* w4h = (_Float16*)(ws + W_OFF + 6193152);      _Float16* w4l = w4h + 2359296;
  _Float16* wrh = (_Float16*)(ws + W_OFF + 15630336);     _Float16* wrl = wrh + 2359296;

  // weight conversion
  wcvt<<<(73728 + 255) / 256, 256, 0, stream>>>(fw1, w1h, w1l, 128, 64);
  wcvt<<<(294912 + 255) / 256, 256, 0, stream>>>(fw2, w2h, w2l, 256, 128);
  wcvt<<<(1179648 + 255) / 256, 256, 0, stream>>>(fw3, w3h, w3l, 512, 256);
  wcvt<<<(2359296 + 255) / 256, 256, 0, stream>>>(fw4, w4h, w4l, 512, 512);
  wcvt<<<(2359296 + 255) / 256, 256, 0, stream>>>(rpw_w, wrh, wrl, 512, 512);

  // pad rings for I0, I1
  zero_ring<<<512, 256, 0, stream>>>(I0h, I0l, 114, 64);
  zero_ring<<<512, 256, 0, stream>>>(I1h, I1l, 58, 128);

  // L0 direct conv (LDS-staged coalesced output)
  conv_l0<<<32 * 49, 256, 0, stream>>>(x, fw0, fb0, I0h, I0l);

  // L1: 64->128 @112, tap-reuse row tiles, XH=2, co128 in-block, KPH=2
  convrow<64, 128, 112, 2, 2, 132, 136, 2><<<dim3(32 * 56 * 2, 1), 256, 0, stream>>>(
      I0h, I0l, w1h, w1l, fb1, I1h, I1l);
  zero_ring<<<512, 256, 0, stream>>>(I2h, I2l, 30, 256);   // I0 region now free
  // L2: 128->256 @56, tap-reuse rows, co-split x2, KPH=2
  convrow<128, 256, 56, 1, 2, 132, 136, 2><<<dim3(32 * 28, 2), 256, 0, stream>>>(
      I1h, I1l, w2h, w2l, fb2, I2h, I2l);
  zero_ring<<<512, 256, 0, stream>>>(I3h, I3l, 16, 512);   // I1 region now free
  // L3: 256->512 @28, tap-reuse rows, co256/block, co-split x2, KPH=2
  convrow<256, 512, 28, 1, 4, 68, 72, 2><<<dim3(32 * 14, 2), 256, 0, stream>>>(
      I2h, I2l, w3h, w3l, fb3, I3h, I3l);
  // L4: 512->512 @14, split-tap x3 -> partials, KPH=2, then finish
  convpool<512, 512, 14, 256, 64, 3, 2, 1><<<dim3(98, 2, 3), 256, 0, stream>>>(
      I3h, I3l, w4h, w4l, nullptr, nullptr, nullptr, part);
  l4_finish<<<(1568 * 128 + 255) / 256, 256, 0, stream>>>(part, fb4, I4h, I4l, feat);

  // RPN: split-tap x9 -> partials, then finish
  rpn_partial<<<dim3(13, 4, 9), 256, 0, stream>>>(I4h, I4l, wrh, wrl, part);
  rpn_finish<<<(800 * 128 + 255) / 256, 256, 0, stream>>>(part, rpw_b, rp512);

  heads_kernel<<<(12000 + 255) / 256, 256, 0, stream>>>(rp512, cls_w, cls_b, reg_w, reg_b, out);
  fc_kernel<<<dim3(32, 20), 256, 0, stream>>>(feat, fc_w, fc_b, out);
  bbox_nms_kernel<<<BATCH, 128, 0, stream>>>(out);
}